// Round 5
// baseline (481.516 us; speedup 1.0000x reference)
//
#include <hip/hip_runtime.h>
#include <hip/hip_bf16.h>
#include <math.h>

#define H 16
#define DH 128
#define HID 2048
#define NB 64
#define LCACHE 4096
#define NS 16
#define PKS 8            // projection K-splits
#define SCALE 0.08838834764831845f

typedef __attribute__((ext_vector_type(8))) short bf16x8;
typedef __attribute__((ext_vector_type(4))) float f32x4;

static __device__ inline unsigned short bfr(float x) {
  union { __hip_bfloat16 b; unsigned short u; } c;
  c.b = __float2bfloat16(x);
  return c.u;
}
static __device__ inline unsigned pkbf(float lo, float hi) {
  return (unsigned)bfr(lo) | ((unsigned)bfr(hi) << 16);
}
union BFU { unsigned u[4]; bf16x8 v; };

// ============ gated projection: partials + last-arriver combine ============
// A[64][2048] row-major. grid (ntiles, PKS). 32 cols per tile, K=256 per split.
// MODE 0: QKV (W1=Wq ld2048 cols<2048 -> q_bf packed*SCALE; W2=Wkv ld256 -> kv_buf)
// MODE 1: Wo -> out f32 + bias
template <int MODE>
__global__ __launch_bounds__(256, 2) void proj_gated(
    const float* __restrict__ A, const float* __restrict__ W1, const float* __restrict__ W2,
    const float* __restrict__ b1, const float* __restrict__ b2,
    float* __restrict__ part, unsigned* __restrict__ q_bf, float* __restrict__ kv_buf,
    float* __restrict__ out, int* __restrict__ cnt) {
  const int nt = blockIdx.x;
  const int ks = blockIdx.y;
  const int n0 = nt * 32;
  const int k0 = ks * 256;
  const int t = threadIdx.x;
  const int m_ = t >> 2;        // 0..63
  const int ng = t & 3;         // cols n0+8*ng .. +8
  __shared__ float As[2][128 * 65];
  __shared__ int lastf;

  const float* Wp; int ldw, wcb;
  const bool iskv = (MODE == 0) && (n0 >= 2048);
  if (iskv) { Wp = W2; ldw = 256; wcb = n0 - 2048; }
  else      { Wp = W1; ldw = 2048; wcb = n0; }
  const int wc = wcb + 8 * ng;

  float acc[8] = {0.f, 0.f, 0.f, 0.f, 0.f, 0.f, 0.f, 0.f};
  float4 ast[8];
#pragma unroll
  for (int j = 0; j < 8; ++j) {
    const int f = t * 4 + j * 1024;
    ast[j] = *(const float4*)(A + (size_t)(f >> 7) * HID + k0 + (f & 127));
  }
  for (int kc = 0; kc < 2; ++kc) {
    float* Ab = As[kc & 1];
#pragma unroll
    for (int j = 0; j < 8; ++j) {
      const int f = t * 4 + j * 1024;
      const int m = f >> 7, k = f & 127;
      Ab[(k + 0) * 65 + m] = ast[j].x;
      Ab[(k + 1) * 65 + m] = ast[j].y;
      Ab[(k + 2) * 65 + m] = ast[j].z;
      Ab[(k + 3) * 65 + m] = ast[j].w;
    }
    if (kc + 1 < 2) {
#pragma unroll
      for (int j = 0; j < 8; ++j) {
        const int f = t * 4 + j * 1024;
        ast[j] = *(const float4*)(A + (size_t)(f >> 7) * HID + k0 + 128 + (f & 127));
      }
    }
    __syncthreads();
    const float* wr = Wp + (size_t)(k0 + kc * 128) * ldw + wc;
#pragma unroll 8
    for (int k = 0; k < 128; ++k) {
      const float a = Ab[k * 65 + m_];
      const float4 w0 = *(const float4*)(wr + (size_t)k * ldw);
      const float4 w1 = *(const float4*)(wr + (size_t)k * ldw + 4);
      acc[0] = fmaf(a, w0.x, acc[0]); acc[1] = fmaf(a, w0.y, acc[1]);
      acc[2] = fmaf(a, w0.z, acc[2]); acc[3] = fmaf(a, w0.w, acc[3]);
      acc[4] = fmaf(a, w1.x, acc[4]); acc[5] = fmaf(a, w1.y, acc[5]);
      acc[6] = fmaf(a, w1.z, acc[6]); acc[7] = fmaf(a, w1.w, acc[7]);
    }
    // single barrier per chunk is safe: buffer parity alternates and the next
    // barrier precedes any same-parity rewrite
    __syncthreads();
  }
  const int NC = (MODE == 0) ? 2304 : 2048;
  const int gcol = ((MODE == 0) ? n0 : n0) + 8 * ng;
  {
    float4 o1, o2;
    o1.x = acc[0]; o1.y = acc[1]; o1.z = acc[2]; o1.w = acc[3];
    o2.x = acc[4]; o2.y = acc[5]; o2.z = acc[6]; o2.w = acc[7];
    float* dst = part + ((size_t)ks * 64 + m_) * NC + gcol;
    *(float4*)dst = o1;
    *(float4*)(dst + 4) = o2;
  }
  __threadfence();
  __syncthreads();
  if (t == 0) lastf = atomicAdd(&cnt[nt], 1);
  __syncthreads();
  if (lastf == PKS - 1) {
    __threadfence();
    // combine 8 partials for this 32-col tile; thread = (m_, 8 cols at gcol)
    float s[8];
#pragma unroll
    for (int i = 0; i < 8; ++i) s[i] = 0.f;
#pragma unroll
    for (int sp2 = 0; sp2 < PKS; ++sp2) {
      const float* src = part + ((size_t)sp2 * 64 + m_) * NC + gcol;
      const float4 p0 = *(const float4*)src;
      const float4 p1 = *(const float4*)(src + 4);
      s[0] += p0.x; s[1] += p0.y; s[2] += p0.z; s[3] += p0.w;
      s[4] += p1.x; s[5] += p1.y; s[6] += p1.z; s[7] += p1.w;
    }
    if (MODE == 1) {
      const float4 bb0 = *(const float4*)(b1 + gcol);
      const float4 bb1 = *(const float4*)(b1 + gcol + 4);
      float4 o1, o2;
      o1.x = s[0] + bb0.x; o1.y = s[1] + bb0.y; o1.z = s[2] + bb0.z; o1.w = s[3] + bb0.w;
      o2.x = s[4] + bb1.x; o2.y = s[5] + bb1.y; o2.z = s[6] + bb1.z; o2.w = s[7] + bb1.w;
      float* dst = out + (size_t)m_ * 2048 + gcol;
      *(float4*)dst = o1;
      *(float4*)(dst + 4) = o2;
    } else if (!iskv) {
      // q: +bias, *SCALE, pack bf16 pairs
      const float4 bb0 = *(const float4*)(b1 + gcol);
      const float4 bb1 = *(const float4*)(b1 + gcol + 4);
      const float v0 = (s[0] + bb0.x) * SCALE, v1 = (s[1] + bb0.y) * SCALE;
      const float v2 = (s[2] + bb0.z) * SCALE, v3 = (s[3] + bb0.w) * SCALE;
      const float v4 = (s[4] + bb1.x) * SCALE, v5 = (s[5] + bb1.y) * SCALE;
      const float v6 = (s[6] + bb1.z) * SCALE, v7 = (s[7] + bb1.w) * SCALE;
      uint4 u;
      u.x = pkbf(v0, v1); u.y = pkbf(v2, v3); u.z = pkbf(v4, v5); u.w = pkbf(v6, v7);
      *(uint4*)(q_bf + (size_t)m_ * 1024 + (gcol >> 1)) = u;
    } else {
      const int kc2 = gcol - 2048;
      const float4 bb0 = *(const float4*)(b2 + kc2);
      const float4 bb1 = *(const float4*)(b2 + kc2 + 4);
      float4 o1, o2;
      o1.x = s[0] + bb0.x; o1.y = s[1] + bb0.y; o1.z = s[2] + bb0.z; o1.w = s[3] + bb0.w;
      o2.x = s[4] + bb1.x; o2.y = s[5] + bb1.y; o2.z = s[6] + bb1.z; o2.w = s[7] + bb1.w;
      float* dst = kv_buf + (size_t)m_ * 256 + kc2;
      *(float4*)dst = o1;
      *(float4*)(dst + 4) = o2;
    }
  }
}

// ============ single-pass MFMA flash attention + gated per-b merge ============
__global__ __launch_bounds__(256, 3) void attn_fused(
    const unsigned* __restrict__ q_bf, const float* __restrict__ kv_buf,
    const float* __restrict__ key_cache, const float* __restrict__ value_cache,
    const int* __restrict__ lens, float* __restrict__ part_out,
    float* __restrict__ part_m, float* __restrict__ part_l,
    int* __restrict__ acnt, float* __restrict__ ctx_buf) {
  const int b = blockIdx.y;
  const int sp = blockIdx.x;
  const int ctx = lens[b];
  const int n0 = (ctx * sp) / NS;
  const int n1 = (ctx * (sp + 1)) / NS;
  const int klen = n1 - n0;
  const bool has_self = (sp == NS - 1);
  const int t = threadIdx.x;

  __shared__ __align__(16) unsigned VtW[128 * 44];   // V transposed, packed row pairs
  __shared__ __align__(16) char sK[16384];           // K bf16 [64][128] swizzled
  __shared__ __align__(16) unsigned Pbuf[16 * 36];
  __shared__ float red1[64], red2[64];
  __shared__ float mrun[2][16], lrun[2][16], sself[16];
  __shared__ int lastf;

  const int lane = t & 63;
  const int wv = t >> 6;
  const int fh = lane & 15;
  const int fg = lane >> 4;
  const int vp = t & 31;
  const int vc = t >> 5;

  if (klen == 0 && !has_self) {
    if (t < H) {
      part_m[((size_t)b * NS + sp) * H + t] = -1e30f;
      part_l[((size_t)b * NS + sp) * H + t] = 0.f;
    }
  } else {
    unsigned* Kl32 = (unsigned*)sK;
    // q fragments straight from packed q_bf
    bf16x8 qf[4];
    const unsigned* qb = q_bf + (size_t)b * 1024 + fh * 64;
#pragma unroll
    for (int s = 0; s < 4; ++s) {
      const uint4 u4 = *(const uint4*)(qb + s * 16 + fg * 4);
      BFU u; u.u[0] = u4.x; u.u[1] = u4.y; u.u[2] = u4.z; u.u[3] = u4.w;
      qf[s] = u.v;
    }
    if (t < 16) { mrun[0][t] = -1e30f; lrun[0][t] = 0.f; }
    if (has_self) {
      float sps = 0.f;
#pragma unroll
      for (int s = 0; s < 4; ++s) {
        BFU u; u.v = qf[s];
        const float* kn = kv_buf + (size_t)b * 256 + s * 32 + fg * 8;
#pragma unroll
        for (int jj = 0; jj < 4; ++jj) {
          sps = fmaf(__uint_as_float(u.u[jj] << 16), kn[2 * jj], sps);
          sps = fmaf(__uint_as_float(u.u[jj] & 0xffff0000u), kn[2 * jj + 1], sps);
        }
      }
      sps += __shfl_xor(sps, 16, 64);
      sps += __shfl_xor(sps, 32, 64);
      if (wv == 0 && lane < 16) sself[lane] = sps;
    }

    const int ntiles = (klen + 63) >> 6;
    const float* ksrc = key_cache + (size_t)b * LCACHE * DH;
    const float* vsrc = value_cache + (size_t)b * LCACHE * DH;
    float4 kst[8], vst[8];
    if (ntiles > 0) {
      const int tb = n0 * DH;
#pragma unroll
      for (int j = 0; j < 8; ++j) {
        const int off = min(tb + j * 1024 + t * 4, LCACHE * DH - 4);
        kst[j] = *(const float4*)(ksrc + off);
      }
      const int r0 = n0 + 2 * vp;
      const float* sa = vsrc + (size_t)min(r0, LCACHE - 1) * DH + vc * 16;
      const float* sb = vsrc + (size_t)min(r0 + 1, LCACHE - 1) * DH + vc * 16;
#pragma unroll
      for (int j = 0; j < 4; ++j) {
        vst[j] = *(const float4*)(sa + j * 4);
        vst[4 + j] = *(const float4*)(sb + j * 4);
      }
    }
    __syncthreads();   // mrun/sself ready

    f32x4 oacc[2];
    oacc[0] = (f32x4){0.f, 0.f, 0.f, 0.f};
    oacc[1] = (f32x4){0.f, 0.f, 0.f, 0.f};
    int par = 0;

    for (int tt = 0; tt < ntiles; ++tt) {
      if (tt > 0) __syncthreads();
#pragma unroll
      for (int j = 0; j < 8; ++j) {
        const int row = j * 8 + (t >> 5);
        const int byteo = ((t & 31) * 8) ^ ((row & 7) << 4);
        const int w0 = row * 64 + (byteo >> 2);
        Kl32[w0] = pkbf(kst[j].x, kst[j].y);
        Kl32[w0 + 1] = pkbf(kst[j].z, kst[j].w);
      }
#pragma unroll
      for (int j = 0; j < 4; ++j) {
        const float4 a = vst[j];
        const float4 b4 = vst[4 + j];
        const int d = vc * 16 + j * 4;
        VtW[(d + 0) * 44 + vp] = pkbf(a.x, b4.x);
        VtW[(d + 1) * 44 + vp] = pkbf(a.y, b4.y);
        VtW[(d + 2) * 44 + vp] = pkbf(a.z, b4.z);
        VtW[(d + 3) * 44 + vp] = pkbf(a.w, b4.w);
      }
      if (tt + 1 < ntiles) {
        const int tb = (n0 + (tt + 1) * 64) * DH;
#pragma unroll
        for (int j = 0; j < 8; ++j) {
          const int off = min(tb + j * 1024 + t * 4, LCACHE * DH - 4);
          kst[j] = *(const float4*)(ksrc + off);
        }
        const int r0 = n0 + (tt + 1) * 64 + 2 * vp;
        const float* sa = vsrc + (size_t)min(r0, LCACHE - 1) * DH + vc * 16;
        const float* sb = vsrc + (size_t)min(r0 + 1, LCACHE - 1) * DH + vc * 16;
#pragma unroll
        for (int j = 0; j < 4; ++j) {
          vst[j] = *(const float4*)(sa + j * 4);
          vst[4 + j] = *(const float4*)(sb + j * 4);
        }
      }
      __syncthreads();

      f32x4 sacc = {0.f, 0.f, 0.f, 0.f};
      const int rr = wv * 16 + fh;
#pragma unroll
      for (int s = 0; s < 4; ++s) {
        const int off = rr * 256 + ((s * 64 + fg * 16) ^ ((rr & 7) << 4));
        const bf16x8 af = *(const bf16x8*)(sK + off);
        sacc = __builtin_amdgcn_mfma_f32_16x16x32_bf16(af, qf[s], sacc, 0, 0, 0);
      }
      const int rloc = wv * 16 + fg * 4;
      const int lim = klen - tt * 64;
      float s0 = (rloc + 0 < lim) ? sacc[0] : -1e30f;
      float s1 = (rloc + 1 < lim) ? sacc[1] : -1e30f;
      float s2 = (rloc + 2 < lim) ? sacc[2] : -1e30f;
      float s3 = (rloc + 3 < lim) ? sacc[3] : -1e30f;
      float ml = fmaxf(fmaxf(s0, s1), fmaxf(s2, s3));
      ml = fmaxf(ml, __shfl_xor(ml, 16, 64));
      ml = fmaxf(ml, __shfl_xor(ml, 32, 64));
      if (fg == 0) red1[wv * 16 + fh] = ml;
      __syncthreads();

      const float4 r0v = *(const float4*)&red1[0 + fg * 4];
      const float4 r1v = *(const float4*)&red1[16 + fg * 4];
      const float4 r2v = *(const float4*)&red1[32 + fg * 4];
      const float4 r3v = *(const float4*)&red1[48 + fg * 4];
      float mt[4];
      mt[0] = fmaxf(fmaxf(r0v.x, r1v.x), fmaxf(r2v.x, r3v.x));
      mt[1] = fmaxf(fmaxf(r0v.y, r1v.y), fmaxf(r2v.y, r3v.y));
      mt[2] = fmaxf(fmaxf(r0v.z, r1v.z), fmaxf(r2v.z, r3v.z));
      mt[3] = fmaxf(fmaxf(r0v.w, r1v.w), fmaxf(r2v.w, r3v.w));
      const float mtf = fmaxf(fmaxf(red1[fh], red1[16 + fh]), fmaxf(red1[32 + fh], red1[48 + fh]));
      const float4 mp4 = *(const float4*)&mrun[par][fg * 4];
      const float mpf = mrun[par][fh];
      const float mnf = fmaxf(mtf, mpf);
      const float p0 = __expf(s0 - mnf);
      const float p1 = __expf(s1 - mnf);
      const float p2 = __expf(s2 - mnf);
      const float p3 = __expf(s3 - mnf);
      {
        const float mpj[4] = {mp4.x, mp4.y, mp4.z, mp4.w};
#pragma unroll
        for (int j = 0; j < 4; ++j) {
          const float mn = fmaxf(mt[j], mpj[j]);
          const float rf = __expf(mpj[j] - mn);
          oacc[0][j] *= rf;
          oacc[1][j] *= rf;
        }
      }
      float sl = p0 + p1 + p2 + p3;
      sl += __shfl_xor(sl, 16, 64);
      sl += __shfl_xor(sl, 32, 64);
      if (fg == 0) red2[wv * 16 + fh] = sl;
      Pbuf[fh * 36 + wv * 8 + fg * 2] = pkbf(p0, p1);
      Pbuf[fh * 36 + wv * 8 + fg * 2 + 1] = pkbf(p2, p3);
      if (t < 16) mrun[par ^ 1][t] = mnf;
      __syncthreads();

      if (t < 16) {
        const float lsum = red2[t] + red2[16 + t] + red2[32 + t] + red2[48 + t];
        lrun[par ^ 1][t] = lrun[par][t] * __expf(mrun[par][t] - mrun[par ^ 1][t]) + lsum;
      }
#pragma unroll
      for (int c2 = 0; c2 < 2; ++c2) {
        const bf16x8 pf = *(const bf16x8*)&Pbuf[fh * 36 + c2 * 16 + fg * 4];
#pragma unroll
        for (int dt = 0; dt < 2; ++dt) {
          const int d = wv * 32 + dt * 16 + fh;
          const bf16x8 vf = *(const bf16x8*)&VtW[d * 44 + c2 * 16 + fg * 4];
          oacc[dt] = __builtin_amdgcn_mfma_f32_16x16x32_bf16(pf, vf, oacc[dt], 0, 0, 0);
        }
      }
      par ^= 1;
    }
    __syncthreads();

    const int parF = par;
    if (has_self) {
      const float4 mp4 = *(const float4*)&mrun[parF][fg * 4];
      const float4 ss4 = *(const float4*)&sself[fg * 4];
      const float vn0 = kv_buf[(size_t)b * 256 + 128 + wv * 32 + fh];
      const float vn1 = kv_buf[(size_t)b * 256 + 128 + wv * 32 + 16 + fh];
      const float mpj[4] = {mp4.x, mp4.y, mp4.z, mp4.w};
      const float ssj[4] = {ss4.x, ss4.y, ss4.z, ss4.w};
#pragma unroll
      for (int j = 0; j < 4; ++j) {
        const float mn = fmaxf(mpj[j], ssj[j]);
        const float rf = __expf(mpj[j] - mn);
        const float ps = __expf(ssj[j] - mn);
        oacc[0][j] = oacc[0][j] * rf + ps * vn0;
        oacc[1][j] = oacc[1][j] * rf + ps * vn1;
      }
      if (t < 16) {
        const float mp = mrun[parF][t], ss = sself[t];
        const float mn = fmaxf(mp, ss);
        part_m[((size_t)b * NS + sp) * H + t] = mn;
        part_l[((size_t)b * NS + sp) * H + t] =
            lrun[parF][t] * __expf(mp - mn) + __expf(ss - mn);
      }
    } else {
      if (t < 16) {
        part_m[((size_t)b * NS + sp) * H + t] = mrun[parF][t];
        part_l[((size_t)b * NS + sp) * H + t] = lrun[parF][t];
      }
    }
    float* po = part_out + ((size_t)b * NS + sp) * H * DH;
#pragma unroll
    for (int dt = 0; dt < 2; ++dt) {
      const int d = wv * 32 + dt * 16 + fh;
#pragma unroll
      for (int j = 0; j < 4; ++j) po[(size_t)(fg * 4 + j) * DH + d] = oacc[dt][j];
    }
  }

  // ---- gate: last split for this b merges all partials -> ctx_buf ----
  __threadfence();
  __syncthreads();
  if (t == 0) lastf = atomicAdd(&acnt[b], 1);
  __syncthreads();
  if (lastf == NS - 1) {
    __threadfence();
    const int h = t >> 4;
    const int d0v = (t & 15) * 8;
    float M = -1e30f;
#pragma unroll
    for (int s2 = 0; s2 < NS; ++s2)
      M = fmaxf(M, part_m[((size_t)b * NS + s2) * H + h]);
    float L = 0.f;
    float o[8];
#pragma unroll
    for (int i = 0; i < 8; ++i) o[i] = 0.f;
#pragma unroll
    for (int s2 = 0; s2 < NS; ++s2) {
      const float m = part_m[((size_t)b * NS + s2) * H + h];
      if (m < -1e29f) continue;
      const float w = __expf(m - M);
      L += w * part_l[((size_t)b * NS + s2) * H + h];
      const float* src = part_out + (((size_t)b * NS + s2) * H + h) * DH + d0v;
      const float4 a = *(const float4*)src;
      const float4 c = *(const float4*)(src + 4);
      o[0] = fmaf(w, a.x, o[0]); o[1] = fmaf(w, a.y, o[1]);
      o[2] = fmaf(w, a.z, o[2]); o[3] = fmaf(w, a.w, o[3]);
      o[4] = fmaf(w, c.x, o[4]); o[5] = fmaf(w, c.y, o[5]);
      o[6] = fmaf(w, c.z, o[6]); o[7] = fmaf(w, c.w, o[7]);
    }
    const float inv = 1.f / L;
    float* dst = ctx_buf + (size_t)b * HID + h * DH + d0v;
    float4 r1, r2;
    r1.x = o[0] * inv; r1.y = o[1] * inv; r1.z = o[2] * inv; r1.w = o[3] * inv;
    r2.x = o[4] * inv; r2.y = o[5] * inv; r2.z = o[6] * inv; r2.w = o[7] * inv;
    *(float4*)dst = r1;
    *(float4*)(dst + 4) = r2;
  }
}

extern "C" void kernel_launch(void* const* d_in, const int* in_sizes, int n_in,
                              void* d_out, int out_size, void* d_ws, size_t ws_size,
                              hipStream_t stream) {
  const float* hidden      = (const float*)d_in[0];
  const float* key_cache   = (const float*)d_in[1];
  const float* value_cache = (const float*)d_in[2];
  const float* Wq  = (const float*)d_in[3];
  const float* bq  = (const float*)d_in[4];
  const float* Wkv = (const float*)d_in[5];
  const float* bkv = (const float*)d_in[6];
  const float* Wo  = (const float*)d_in[7];
  const float* bo  = (const float*)d_in[8];
  const int*   lens = (const int*)d_in[9];
  float* out = (float*)d_out;

  float* ws = (float*)d_ws;
  float*    part1    = ws;                                     // PKS*64*2304
  unsigned* q_bf     = (unsigned*)(part1 + (size_t)PKS * 64 * 2304);  // 64*1024 u32
  float*    kv_buf   = (float*)(q_bf + (size_t)64 * 1024);     // 64*256
  float*    part_out = kv_buf + (size_t)64 * 256;              // 64*NS*H*DH
  float*    part_m   = part_out + (size_t)64 * NS * H * DH;    // 64*NS*H
  float*    part_l   = part_m + (size_t)64 * NS * H;           // 64*NS*H
  float*    ctx_buf  = part_l + (size_t)64 * NS * H;           // 64*2048
  float*    part2    = ctx_buf + (size_t)64 * HID;             // PKS*64*2048
  int*      cnt      = (int*)(part2 + (size_t)PKS * 64 * 2048);
  int* cnt_qkv  = cnt;        // 72
  int* cnt_attn = cnt + 72;   // 64
  int* cnt_wo   = cnt + 136;  // 64

  hipMemsetAsync(cnt, 0, 200 * sizeof(int), stream);
  proj_gated<0><<<dim3(72, PKS), dim3(256), 0, stream>>>(
      hidden, Wq, Wkv, bq, bkv, part1, q_bf, kv_buf, nullptr, cnt_qkv);
  attn_fused<<<dim3(NS, NB), dim3(256), 0, stream>>>(
      q_bf, kv_buf, key_cache, value_cache, lens, part_out, part_m, part_l,
      cnt_attn, ctx_buf);
  proj_gated<1><<<dim3(64, PKS), dim3(256), 0, stream>>>(
      ctx_buf, Wo, Wo, bo, bo, part2, nullptr, nullptr, out, cnt_wo);
}

// Round 6
// 137.173 us; speedup vs baseline: 3.5103x; 3.5103x over previous
//
#include <hip/hip_runtime.h>
#include <hip/hip_bf16.h>
#include <math.h>

#define H 16
#define DH 128
#define HID 2048
#define NB 64
#define LCACHE 4096
#define NS 16
#define PKS 8            // projection K-splits
#define SCALE 0.08838834764831845f

typedef __attribute__((ext_vector_type(8))) short bf16x8;
typedef __attribute__((ext_vector_type(4))) float f32x4;

static __device__ inline unsigned short bfr(float x) {
  union { __hip_bfloat16 b; unsigned short u; } c;
  c.b = __float2bfloat16(x);
  return c.u;
}
static __device__ inline unsigned pkbf(float lo, float hi) {
  return (unsigned)bfr(lo) | ((unsigned)bfr(hi) << 16);
}
union BFU { unsigned u[4]; bf16x8 v; };

// ============ projection partials: row-major A, in-LDS transpose ============
// A[64][2048]. grid (ntiles, PKS). 32 cols/tile, K=256/split.
// MODE 0: QKV (W1=Wq ld2048 for cols<2048; W2=Wkv ld256 for cols>=2048), NC=2304
// MODE 1: Wo, NC=2048
template <int MODE>
__global__ __launch_bounds__(256, 2) void proj_part(
    const float* __restrict__ A, const float* __restrict__ W1, const float* __restrict__ W2,
    float* __restrict__ part) {
  const int nt = blockIdx.x;
  const int ks = blockIdx.y;
  const int n0 = nt * 32;
  const int k0 = ks * 256;
  const int t = threadIdx.x;
  const int m_ = t >> 2;        // 0..63
  const int ng = t & 3;         // col group of 8
  __shared__ float As[2][128 * 65];

  const float* Wp; int ldw, wcb;
  const bool iskv = (MODE == 0) && (n0 >= 2048);
  if (iskv) { Wp = W2; ldw = 256; wcb = n0 - 2048; }
  else      { Wp = W1; ldw = 2048; wcb = n0; }
  const int wc = wcb + 8 * ng;

  float acc[8] = {0.f, 0.f, 0.f, 0.f, 0.f, 0.f, 0.f, 0.f};
  float4 ast[8];
#pragma unroll
  for (int j = 0; j < 8; ++j) {
    const int f = t * 4 + j * 1024;
    ast[j] = *(const float4*)(A + (size_t)(f >> 7) * HID + k0 + (f & 127));
  }
  for (int kc = 0; kc < 2; ++kc) {
    float* Ab = As[kc & 1];
#pragma unroll
    for (int j = 0; j < 8; ++j) {
      const int f = t * 4 + j * 1024;
      const int m = f >> 7, k = f & 127;
      Ab[(k + 0) * 65 + m] = ast[j].x;
      Ab[(k + 1) * 65 + m] = ast[j].y;
      Ab[(k + 2) * 65 + m] = ast[j].z;
      Ab[(k + 3) * 65 + m] = ast[j].w;
    }
    if (kc + 1 < 2) {
#pragma unroll
      for (int j = 0; j < 8; ++j) {
        const int f = t * 4 + j * 1024;
        ast[j] = *(const float4*)(A + (size_t)(f >> 7) * HID + k0 + 128 + (f & 127));
      }
    }
    __syncthreads();
    const float* wr = Wp + (size_t)(k0 + kc * 128) * ldw + wc;
#pragma unroll 8
    for (int k = 0; k < 128; ++k) {
      const float a = Ab[k * 65 + m_];
      const float4 w0 = *(const float4*)(wr + (size_t)k * ldw);
      const float4 w1 = *(const float4*)(wr + (size_t)k * ldw + 4);
      acc[0] = fmaf(a, w0.x, acc[0]); acc[1] = fmaf(a, w0.y, acc[1]);
      acc[2] = fmaf(a, w0.z, acc[2]); acc[3] = fmaf(a, w0.w, acc[3]);
      acc[4] = fmaf(a, w1.x, acc[4]); acc[5] = fmaf(a, w1.y, acc[5]);
      acc[6] = fmaf(a, w1.z, acc[6]); acc[7] = fmaf(a, w1.w, acc[7]);
    }
    __syncthreads();
  }
  const int NC = (MODE == 0) ? 2304 : 2048;
  const int gcol = n0 + 8 * ng;
  float4 o1, o2;
  o1.x = acc[0]; o1.y = acc[1]; o1.z = acc[2]; o1.w = acc[3];
  o2.x = acc[4]; o2.y = acc[5]; o2.z = acc[6]; o2.w = acc[7];
  float* dst = part + ((size_t)ks * 64 + m_) * NC + gcol;
  *(float4*)dst = o1;
  *(float4*)(dst + 4) = o2;
}

// ============ QKV combine: sum partials + bias; q -> bf16 packed*SCALE ============
__global__ __launch_bounds__(256) void qkv_combine(
    const float* __restrict__ part, const float* __restrict__ bq,
    const float* __restrict__ bkv, unsigned* __restrict__ q_bf,
    float* __restrict__ kv_buf) {
  const int gid = blockIdx.x * 256 + threadIdx.x;
  const int row = gid / 288;
  const int col = (gid - row * 288) * 8;
  float s[8];
#pragma unroll
  for (int i = 0; i < 8; ++i) s[i] = 0.f;
#pragma unroll
  for (int sp = 0; sp < PKS; ++sp) {
    const float* src = part + ((size_t)sp * 64 + row) * 2304 + col;
    const float4 p0 = *(const float4*)src;
    const float4 p1 = *(const float4*)(src + 4);
    s[0] += p0.x; s[1] += p0.y; s[2] += p0.z; s[3] += p0.w;
    s[4] += p1.x; s[5] += p1.y; s[6] += p1.z; s[7] += p1.w;
  }
  if (col < 2048) {
    const float4 bb0 = *(const float4*)(bq + col);
    const float4 bb1 = *(const float4*)(bq + col + 4);
    const float v0 = (s[0] + bb0.x) * SCALE, v1 = (s[1] + bb0.y) * SCALE;
    const float v2 = (s[2] + bb0.z) * SCALE, v3 = (s[3] + bb0.w) * SCALE;
    const float v4 = (s[4] + bb1.x) * SCALE, v5 = (s[5] + bb1.y) * SCALE;
    const float v6 = (s[6] + bb1.z) * SCALE, v7 = (s[7] + bb1.w) * SCALE;
    uint4 u;
    u.x = pkbf(v0, v1); u.y = pkbf(v2, v3); u.z = pkbf(v4, v5); u.w = pkbf(v6, v7);
    *(uint4*)(q_bf + (size_t)row * 1024 + (col >> 1)) = u;
  } else {
    const int kc = col - 2048;
    const float4 bb0 = *(const float4*)(bkv + kc);
    const float4 bb1 = *(const float4*)(bkv + kc + 4);
    float4 o1, o2;
    o1.x = s[0] + bb0.x; o1.y = s[1] + bb0.y; o1.z = s[2] + bb0.z; o1.w = s[3] + bb0.w;
    o2.x = s[4] + bb1.x; o2.y = s[5] + bb1.y; o2.z = s[6] + bb1.z; o2.w = s[7] + bb1.w;
    float* dst = kv_buf + (size_t)row * 256 + kc;
    *(float4*)dst = o1;
    *(float4*)(dst + 4) = o2;
  }
}

// ============ Wo combine: sum partials + bias -> out ============
__global__ __launch_bounds__(256) void wo_combine(
    const float* __restrict__ part, const float* __restrict__ bo,
    float* __restrict__ out) {
  const int f = (blockIdx.x * 256 + threadIdx.x) * 4;
  const int row = f >> 11;
  const int c = f & 2047;
  float4 s = *(const float4*)(part + (size_t)row * 2048 + c);
#pragma unroll
  for (int sp = 1; sp < PKS; ++sp) {
    const float4 p = *(const float4*)(part + ((size_t)sp * 64 + row) * 2048 + c);
    s.x += p.x; s.y += p.y; s.z += p.z; s.w += p.w;
  }
  const float4 bb = *(const float4*)(bo + c);
  s.x += bb.x; s.y += bb.y; s.z += bb.z; s.w += bb.w;
  *(float4*)(out + (size_t)row * 2048 + c) = s;
}

// ============ single-pass MFMA flash-decoding attention ============
__global__ __launch_bounds__(256, 3) void attn_fused(
    const unsigned* __restrict__ q_bf, const float* __restrict__ kv_buf,
    const float* __restrict__ key_cache, const float* __restrict__ value_cache,
    const int* __restrict__ lens, float* __restrict__ part_out,
    float* __restrict__ part_m, float* __restrict__ part_l) {
  const int b = blockIdx.y;
  const int sp = blockIdx.x;
  const int ctx = lens[b];
  const int n0 = (ctx * sp) / NS;
  const int n1 = (ctx * (sp + 1)) / NS;
  const int klen = n1 - n0;
  const bool has_self = (sp == NS - 1);
  const int t = threadIdx.x;

  if (klen == 0 && !has_self) {
    if (t < H) {
      part_m[((size_t)b * NS + sp) * H + t] = -1e30f;
      part_l[((size_t)b * NS + sp) * H + t] = 0.f;
    }
    return;
  }

  __shared__ __align__(16) unsigned VtW[128 * 44];   // V transposed, packed row pairs
  __shared__ __align__(16) char sK[16384];           // K bf16 [64][128] swizzled
  __shared__ __align__(16) unsigned Pbuf[16 * 36];
  __shared__ float red1[64], red2[64];
  __shared__ float mrun[2][16], lrun[2][16], sself[16];

  const int lane = t & 63;
  const int wv = t >> 6;
  const int fh = lane & 15;
  const int fg = lane >> 4;
  const int vp = t & 31;
  const int vc = t >> 5;

  unsigned* Kl32 = (unsigned*)sK;
  // q fragments straight from packed q_bf
  bf16x8 qf[4];
  const unsigned* qb = q_bf + (size_t)b * 1024 + fh * 64;
#pragma unroll
  for (int s = 0; s < 4; ++s) {
    const uint4 u4 = *(const uint4*)(qb + s * 16 + fg * 4);
    BFU u; u.u[0] = u4.x; u.u[1] = u4.y; u.u[2] = u4.z; u.u[3] = u4.w;
    qf[s] = u.v;
  }
  if (t < 16) { mrun[0][t] = -1e30f; lrun[0][t] = 0.f; }
  if (has_self) {
    float sps = 0.f;
#pragma unroll
    for (int s = 0; s < 4; ++s) {
      BFU u; u.v = qf[s];
      const float* kn = kv_buf + (size_t)b * 256 + s * 32 + fg * 8;
#pragma unroll
      for (int jj = 0; jj < 4; ++jj) {
        sps = fmaf(__uint_as_float(u.u[jj] << 16), kn[2 * jj], sps);
        sps = fmaf(__uint_as_float(u.u[jj] & 0xffff0000u), kn[2 * jj + 1], sps);
      }
    }
    sps += __shfl_xor(sps, 16, 64);
    sps += __shfl_xor(sps, 32, 64);
    if (wv == 0 && lane < 16) sself[lane] = sps;
  }

  const int ntiles = (klen + 63) >> 6;
  const float* ksrc = key_cache + (size_t)b * LCACHE * DH;
  const float* vsrc = value_cache + (size_t)b * LCACHE * DH;
  float4 kst[8], vst[8];
  if (ntiles > 0) {
    const int tb = n0 * DH;
#pragma unroll
    for (int j = 0; j < 8; ++j) {
      const int off = min(tb + j * 1024 + t * 4, LCACHE * DH - 4);
      kst[j] = *(const float4*)(ksrc + off);
    }
    const int r0 = n0 + 2 * vp;
    const float* sa = vsrc + (size_t)min(r0, LCACHE - 1) * DH + vc * 16;
    const float* sb = vsrc + (size_t)min(r0 + 1, LCACHE - 1) * DH + vc * 16;
#pragma unroll
    for (int j = 0; j < 4; ++j) {
      vst[j] = *(const float4*)(sa + j * 4);
      vst[4 + j] = *(const float4*)(sb + j * 4);
    }
  }
  __syncthreads();   // mrun/sself ready

  f32x4 oacc[2];
  oacc[0] = (f32x4){0.f, 0.f, 0.f, 0.f};
  oacc[1] = (f32x4){0.f, 0.f, 0.f, 0.f};
  int par = 0;

  for (int tt = 0; tt < ntiles; ++tt) {
    if (tt > 0) __syncthreads();
#pragma unroll
    for (int j = 0; j < 8; ++j) {
      const int row = j * 8 + (t >> 5);
      const int byteo = ((t & 31) * 8) ^ ((row & 7) << 4);
      const int w0 = row * 64 + (byteo >> 2);
      Kl32[w0] = pkbf(kst[j].x, kst[j].y);
      Kl32[w0 + 1] = pkbf(kst[j].z, kst[j].w);
    }
#pragma unroll
    for (int j = 0; j < 4; ++j) {
      const float4 a = vst[j];
      const float4 b4 = vst[4 + j];
      const int d = vc * 16 + j * 4;
      VtW[(d + 0) * 44 + vp] = pkbf(a.x, b4.x);
      VtW[(d + 1) * 44 + vp] = pkbf(a.y, b4.y);
      VtW[(d + 2) * 44 + vp] = pkbf(a.z, b4.z);
      VtW[(d + 3) * 44 + vp] = pkbf(a.w, b4.w);
    }
    if (tt + 1 < ntiles) {
      const int tb = (n0 + (tt + 1) * 64) * DH;
#pragma unroll
      for (int j = 0; j < 8; ++j) {
        const int off = min(tb + j * 1024 + t * 4, LCACHE * DH - 4);
        kst[j] = *(const float4*)(ksrc + off);
      }
      const int r0 = n0 + (tt + 1) * 64 + 2 * vp;
      const float* sa = vsrc + (size_t)min(r0, LCACHE - 1) * DH + vc * 16;
      const float* sb = vsrc + (size_t)min(r0 + 1, LCACHE - 1) * DH + vc * 16;
#pragma unroll
      for (int j = 0; j < 4; ++j) {
        vst[j] = *(const float4*)(sa + j * 4);
        vst[4 + j] = *(const float4*)(sb + j * 4);
      }
    }
    __syncthreads();

    f32x4 sacc = {0.f, 0.f, 0.f, 0.f};
    const int rr = wv * 16 + fh;
#pragma unroll
    for (int s = 0; s < 4; ++s) {
      const int off = rr * 256 + ((s * 64 + fg * 16) ^ ((rr & 7) << 4));
      const bf16x8 af = *(const bf16x8*)(sK + off);
      sacc = __builtin_amdgcn_mfma_f32_16x16x32_bf16(af, qf[s], sacc, 0, 0, 0);
    }
    const int rloc = wv * 16 + fg * 4;
    const int lim = klen - tt * 64;
    float s0 = (rloc + 0 < lim) ? sacc[0] : -1e30f;
    float s1 = (rloc + 1 < lim) ? sacc[1] : -1e30f;
    float s2 = (rloc + 2 < lim) ? sacc[2] : -1e30f;
    float s3 = (rloc + 3 < lim) ? sacc[3] : -1e30f;
    float ml = fmaxf(fmaxf(s0, s1), fmaxf(s2, s3));
    ml = fmaxf(ml, __shfl_xor(ml, 16, 64));
    ml = fmaxf(ml, __shfl_xor(ml, 32, 64));
    if (fg == 0) red1[wv * 16 + fh] = ml;
    __syncthreads();

    const float4 r0v = *(const float4*)&red1[0 + fg * 4];
    const float4 r1v = *(const float4*)&red1[16 + fg * 4];
    const float4 r2v = *(const float4*)&red1[32 + fg * 4];
    const float4 r3v = *(const float4*)&red1[48 + fg * 4];
    float mt[4];
    mt[0] = fmaxf(fmaxf(r0v.x, r1v.x), fmaxf(r2v.x, r3v.x));
    mt[1] = fmaxf(fmaxf(r0v.y, r1v.y), fmaxf(r2v.y, r3v.y));
    mt[2] = fmaxf(fmaxf(r0v.z, r1v.z), fmaxf(r2v.z, r3v.z));
    mt[3] = fmaxf(fmaxf(r0v.w, r1v.w), fmaxf(r2v.w, r3v.w));
    const float mtf = fmaxf(fmaxf(red1[fh], red1[16 + fh]), fmaxf(red1[32 + fh], red1[48 + fh]));
    const float4 mp4 = *(const float4*)&mrun[par][fg * 4];
    const float mpf = mrun[par][fh];
    const float mnf = fmaxf(mtf, mpf);
    const float p0 = __expf(s0 - mnf);
    const float p1 = __expf(s1 - mnf);
    const float p2 = __expf(s2 - mnf);
    const float p3 = __expf(s3 - mnf);
    {
      const float mpj[4] = {mp4.x, mp4.y, mp4.z, mp4.w};
#pragma unroll
      for (int j = 0; j < 4; ++j) {
        const float mn = fmaxf(mt[j], mpj[j]);
        const float rf = __expf(mpj[j] - mn);
        oacc[0][j] *= rf;
        oacc[1][j] *= rf;
      }
    }
    float sl = p0 + p1 + p2 + p3;
    sl += __shfl_xor(sl, 16, 64);
    sl += __shfl_xor(sl, 32, 64);
    if (fg == 0) red2[wv * 16 + fh] = sl;
    Pbuf[fh * 36 + wv * 8 + fg * 2] = pkbf(p0, p1);
    Pbuf[fh * 36 + wv * 8 + fg * 2 + 1] = pkbf(p2, p3);
    if (t < 16) mrun[par ^ 1][t] = mnf;
    __syncthreads();

    if (t < 16) {
      const float lsum = red2[t] + red2[16 + t] + red2[32 + t] + red2[48 + t];
      lrun[par ^ 1][t] = lrun[par][t] * __expf(mrun[par][t] - mrun[par ^ 1][t]) + lsum;
    }
#pragma unroll
    for (int c2 = 0; c2 < 2; ++c2) {
      const bf16x8 pf = *(const bf16x8*)&Pbuf[fh * 36 + c2 * 16 + fg * 4];
#pragma unroll
      for (int dt = 0; dt < 2; ++dt) {
        const int d = wv * 32 + dt * 16 + fh;
        const bf16x8 vf = *(const bf16x8*)&VtW[d * 44 + c2 * 16 + fg * 4];
        oacc[dt] = __builtin_amdgcn_mfma_f32_16x16x32_bf16(pf, vf, oacc[dt], 0, 0, 0);
      }
    }
    par ^= 1;
  }
  __syncthreads();

  const int parF = par;
  if (has_self) {
    const float4 mp4 = *(const float4*)&mrun[parF][fg * 4];
    const float4 ss4 = *(const float4*)&sself[fg * 4];
    const float vn0 = kv_buf[(size_t)b * 256 + 128 + wv * 32 + fh];
    const float vn1 = kv_buf[(size_t)b * 256 + 128 + wv * 32 + 16 + fh];
    const float mpj[4] = {mp4.x, mp4.y, mp4.z, mp4.w};
    const float ssj[4] = {ss4.x, ss4.y, ss4.z, ss4.w};
#pragma unroll
    for (int j = 0; j < 4; ++j) {
      const float mn = fmaxf(mpj[j], ssj[j]);
      const float rf = __expf(mpj[j] - mn);
      const float ps = __expf(ssj[j] - mn);
      oacc[0][j] = oacc[0][j] * rf + ps * vn0;
      oacc[1][j] = oacc[1][j] * rf + ps * vn1;
    }
    if (t < 16) {
      const float mp = mrun[parF][t], ss = sself[t];
      const float mn = fmaxf(mp, ss);
      part_m[((size_t)b * NS + sp) * H + t] = mn;
      part_l[((size_t)b * NS + sp) * H + t] =
          lrun[parF][t] * __expf(mp - mn) + __expf(ss - mn);
    }
  } else {
    if (t < 16) {
      part_m[((size_t)b * NS + sp) * H + t] = mrun[parF][t];
      part_l[((size_t)b * NS + sp) * H + t] = lrun[parF][t];
    }
  }
  float* po = part_out + ((size_t)b * NS + sp) * H * DH;
#pragma unroll
  for (int dt = 0; dt < 2; ++dt) {
    const int d = wv * 32 + dt * 16 + fh;
#pragma unroll
    for (int j = 0; j < 4; ++j) po[(size_t)(fg * 4 + j) * DH + d] = oacc[dt][j];
  }
}

// ============ merge flash-decoding splits -> ctx_buf [64][2048] ============
__global__ __launch_bounds__(256) void attn_combine(
    const float* __restrict__ part_out, const float* __restrict__ part_m,
    const float* __restrict__ part_l, float* __restrict__ ctx_buf) {
  const int b = blockIdx.x;
  const int dq = blockIdx.y;
  const int t = threadIdx.x;
  const int h = t >> 4;
  const int d = dq * 32 + (t & 15) * 2;
  float M = -1e30f;
#pragma unroll
  for (int sp = 0; sp < NS; ++sp)
    M = fmaxf(M, part_m[((size_t)b * NS + sp) * H + h]);
  float L = 0.f, o0 = 0.f, o1 = 0.f;
#pragma unroll
  for (int sp = 0; sp < NS; ++sp) {
    const float m = part_m[((size_t)b * NS + sp) * H + h];
    if (m < -1e29f) continue;
    const float w = __expf(m - M);
    L += w * part_l[((size_t)b * NS + sp) * H + h];
    const float2 a = *(const float2*)(part_out + (((size_t)b * NS + sp) * H + h) * DH + d);
    o0 = fmaf(w, a.x, o0);
    o1 = fmaf(w, a.y, o1);
  }
  const float inv = 1.f / L;
  float* dst = ctx_buf + (size_t)b * HID + h * DH + d;
  dst[0] = o0 * inv;
  dst[1] = o1 * inv;
}

extern "C" void kernel_launch(void* const* d_in, const int* in_sizes, int n_in,
                              void* d_out, int out_size, void* d_ws, size_t ws_size,
                              hipStream_t stream) {
  const float* hidden      = (const float*)d_in[0];
  const float* key_cache   = (const float*)d_in[1];
  const float* value_cache = (const float*)d_in[2];
  const float* Wq  = (const float*)d_in[3];
  const float* bq  = (const float*)d_in[4];
  const float* Wkv = (const float*)d_in[5];
  const float* bkv = (const float*)d_in[6];
  const float* Wo  = (const float*)d_in[7];
  const float* bo  = (const float*)d_in[8];
  const int*   lens = (const int*)d_in[9];
  float* out = (float*)d_out;

  float* ws = (float*)d_ws;
  float*    part1    = ws;                                           // PKS*64*2304
  unsigned* q_bf     = (unsigned*)(part1 + (size_t)PKS * 64 * 2304); // 64*1024 u32
  float*    kv_buf   = (float*)(q_bf + (size_t)64 * 1024);           // 64*256
  float*    part_out = kv_buf + (size_t)64 * 256;                    // 64*NS*H*DH
  float*    part_m   = part_out + (size_t)64 * NS * H * DH;          // 64*NS*H
  float*    part_l   = part_m + (size_t)64 * NS * H;                 // 64*NS*H
  float*    ctx_buf  = part_l + (size_t)64 * NS * H;                 // 64*2048
  float*    part2    = ctx_buf + (size_t)64 * HID;                   // PKS*64*2048

  proj_part<0><<<dim3(72, PKS), dim3(256), 0, stream>>>(hidden, Wq, Wkv, part1);
  qkv_combine<<<dim3(72), dim3(256), 0, stream>>>(part1, bq, bkv, q_bf, kv_buf);
  attn_fused<<<dim3(NS, NB), dim3(256), 0, stream>>>(
      q_bf, kv_buf, key_cache, value_cache, lens, part_out, part_m, part_l);
  attn_combine<<<dim3(NB, 4), dim3(256), 0, stream>>>(part_out, part_m, part_l, ctx_buf);
  proj_part<1><<<dim3(64, PKS), dim3(256), 0, stream>>>(ctx_buf, Wo, Wo, part2);
  wo_combine<<<dim3(128), dim3(256), 0, stream>>>(part2, bo, out);
}

// Round 7
// 103.150 us; speedup vs baseline: 4.6681x; 1.3298x over previous
//
#include <hip/hip_runtime.h>
#include <hip/hip_bf16.h>
#include <math.h>

#define H 16
#define DH 128
#define HID 2048
#define NB 64
#define LCACHE 4096
#define NS 16
#define KS 16            // projection K-splits
#define SCALE 0.08838834764831845f

typedef __attribute__((ext_vector_type(8))) short bf16x8;
typedef __attribute__((ext_vector_type(4))) float f32x4;

static __device__ inline unsigned short bfr(float x) {
  union { __hip_bfloat16 b; unsigned short u; } c;
  c.b = __float2bfloat16(x);
  return c.u;
}
static __device__ inline unsigned pkbf(float lo, float hi) {
  return (unsigned)bfr(lo) | ((unsigned)bfr(hi) << 16);
}
union BFU { unsigned u[4]; bf16x8 v; };

// ============ projection partials: row-major A, conflict-free in-LDS transpose ============
// A[64][2048]. grid (ncol/128, KS). 128 cols/tile, 128 k per split.
// MODE 0: QKV (W1=Wq ld2048 cols<2048; W2=Wkv ld256 cols>=2048), NC=2304
// MODE 1: Wo, NC=2048
template <int MODE>
__global__ __launch_bounds__(256, 4) void proj_v3(
    const float* __restrict__ A, const float* __restrict__ W1, const float* __restrict__ W2,
    float* __restrict__ part) {
  const int n0 = blockIdx.x * 128;
  const int k0 = blockIdx.y * 128;
  __shared__ float As[128 * 68];
  const int t = threadIdx.x;

  // stage A[64][k0..k0+128] transposed -> As[k][m]
  // thread: m = t&63, kq = t>>6 (32 k's); reads 128B contiguous; writes lanes at consecutive m
  {
    const int m = t & 63;
    const int kq = t >> 6;
    const float* src = A + (size_t)m * HID + k0 + kq * 32;
#pragma unroll
    for (int c = 0; c < 8; ++c) {
      const float4 a4 = *(const float4*)(src + c * 4);
      const int kk = kq * 32 + c * 4;
      As[(kk + 0) * 68 + m] = a4.x;
      As[(kk + 1) * 68 + m] = a4.y;
      As[(kk + 2) * 68 + m] = a4.z;
      As[(kk + 3) * 68 + m] = a4.w;
    }
  }
  __syncthreads();

  const int m0 = (t & 15) * 4;
  const int ng = (t >> 4) * 8;
  const float* Wp;
  int ldw, wc;
  const bool iskv = (MODE == 0) && (n0 >= 2048);
  if (iskv) { Wp = W2; ldw = 256; wc = n0 - 2048 + ng; }
  else      { Wp = W1; ldw = 2048; wc = n0 + ng; }

  float acc[4][8];
#pragma unroll
  for (int i = 0; i < 4; ++i)
#pragma unroll
    for (int j = 0; j < 8; ++j) acc[i][j] = 0.f;
#pragma unroll 4
  for (int k = 0; k < 128; ++k) {
    const float4 a4 = *(const float4*)&As[k * 68 + m0];
    const float* wrow = Wp + (size_t)(k0 + k) * ldw + wc;
    const float4 w0 = *(const float4*)(wrow);
    const float4 w1 = *(const float4*)(wrow + 4);
    const float av[4] = {a4.x, a4.y, a4.z, a4.w};
    const float wv[8] = {w0.x, w0.y, w0.z, w0.w, w1.x, w1.y, w1.z, w1.w};
#pragma unroll
    for (int i = 0; i < 4; ++i)
#pragma unroll
      for (int j = 0; j < 8; ++j) acc[i][j] = fmaf(av[i], wv[j], acc[i][j]);
  }
  const int NC = (MODE == 0) ? 2304 : 2048;
#pragma unroll
  for (int i = 0; i < 4; ++i) {
    float4 o1, o2;
    o1.x = acc[i][0]; o1.y = acc[i][1]; o1.z = acc[i][2]; o1.w = acc[i][3];
    o2.x = acc[i][4]; o2.y = acc[i][5]; o2.z = acc[i][6]; o2.w = acc[i][7];
    float* dst = part + ((size_t)blockIdx.y * 64 + m0 + i) * NC + n0 + ng;
    *(float4*)dst = o1;
    *(float4*)(dst + 4) = o2;
  }
}

// ============ QKV combine: sum partials + bias; q -> bf16 packed*SCALE ============
__global__ __launch_bounds__(256) void qkv_combine(
    const float* __restrict__ part, const float* __restrict__ bq,
    const float* __restrict__ bkv, unsigned* __restrict__ q_bf,
    float* __restrict__ kv_buf) {
  const int gid = blockIdx.x * 256 + threadIdx.x;
  const int row = gid / 288;
  const int col = (gid - row * 288) * 8;
  float s[8];
#pragma unroll
  for (int i = 0; i < 8; ++i) s[i] = 0.f;
#pragma unroll
  for (int sp = 0; sp < KS; ++sp) {
    const float* src = part + ((size_t)sp * 64 + row) * 2304 + col;
    const float4 p0 = *(const float4*)src;
    const float4 p1 = *(const float4*)(src + 4);
    s[0] += p0.x; s[1] += p0.y; s[2] += p0.z; s[3] += p0.w;
    s[4] += p1.x; s[5] += p1.y; s[6] += p1.z; s[7] += p1.w;
  }
  if (col < 2048) {
    const float4 bb0 = *(const float4*)(bq + col);
    const float4 bb1 = *(const float4*)(bq + col + 4);
    const float v0 = (s[0] + bb0.x) * SCALE, v1 = (s[1] + bb0.y) * SCALE;
    const float v2 = (s[2] + bb0.z) * SCALE, v3 = (s[3] + bb0.w) * SCALE;
    const float v4 = (s[4] + bb1.x) * SCALE, v5 = (s[5] + bb1.y) * SCALE;
    const float v6 = (s[6] + bb1.z) * SCALE, v7 = (s[7] + bb1.w) * SCALE;
    uint4 u;
    u.x = pkbf(v0, v1); u.y = pkbf(v2, v3); u.z = pkbf(v4, v5); u.w = pkbf(v6, v7);
    *(uint4*)(q_bf + (size_t)row * 1024 + (col >> 1)) = u;
  } else {
    const int kc = col - 2048;
    const float4 bb0 = *(const float4*)(bkv + kc);
    const float4 bb1 = *(const float4*)(bkv + kc + 4);
    float4 o1, o2;
    o1.x = s[0] + bb0.x; o1.y = s[1] + bb0.y; o1.z = s[2] + bb0.z; o1.w = s[3] + bb0.w;
    o2.x = s[4] + bb1.x; o2.y = s[5] + bb1.y; o2.z = s[6] + bb1.z; o2.w = s[7] + bb1.w;
    float* dst = kv_buf + (size_t)row * 256 + kc;
    *(float4*)dst = o1;
    *(float4*)(dst + 4) = o2;
  }
}

// ============ Wo combine: sum partials + bias -> out ============
__global__ __launch_bounds__(256) void wo_combine(
    const float* __restrict__ part, const float* __restrict__ bo,
    float* __restrict__ out) {
  const int f = (blockIdx.x * 256 + threadIdx.x) * 4;
  const int row = f >> 11;
  const int c = f & 2047;
  float4 s = *(const float4*)(part + (size_t)row * 2048 + c);
#pragma unroll
  for (int sp = 1; sp < KS; ++sp) {
    const float4 p = *(const float4*)(part + ((size_t)sp * 64 + row) * 2048 + c);
    s.x += p.x; s.y += p.y; s.z += p.z; s.w += p.w;
  }
  const float4 bb = *(const float4*)(bo + c);
  s.x += bb.x; s.y += bb.y; s.z += bb.z; s.w += bb.w;
  *(float4*)(out + (size_t)row * 2048 + c) = s;
}

// ============ single-pass MFMA flash-decoding attention ============
__global__ __launch_bounds__(256, 3) void attn_fused(
    const unsigned* __restrict__ q_bf, const float* __restrict__ kv_buf,
    const float* __restrict__ key_cache, const float* __restrict__ value_cache,
    const int* __restrict__ lens, float* __restrict__ part_out,
    float* __restrict__ part_m, float* __restrict__ part_l) {
  const int b = blockIdx.y;
  const int sp = blockIdx.x;
  const int ctx = lens[b];
  const int n0 = (ctx * sp) / NS;
  const int n1 = (ctx * (sp + 1)) / NS;
  const int klen = n1 - n0;
  const bool has_self = (sp == NS - 1);
  const int t = threadIdx.x;

  if (klen == 0 && !has_self) {
    if (t < H) {
      part_m[((size_t)b * NS + sp) * H + t] = -1e30f;
      part_l[((size_t)b * NS + sp) * H + t] = 0.f;
    }
    return;
  }

  __shared__ __align__(16) unsigned VtW[128 * 44];   // V transposed, packed row pairs
  __shared__ __align__(16) char sK[16384];           // K bf16 [64][128] swizzled
  __shared__ __align__(16) unsigned Pbuf[16 * 36];
  __shared__ float red1[64], red2[64];
  __shared__ float mrun[2][16], lrun[2][16], sself[16];

  const int lane = t & 63;
  const int wv = t >> 6;
  const int fh = lane & 15;
  const int fg = lane >> 4;
  const int vp = t & 31;
  const int vc = t >> 5;

  unsigned* Kl32 = (unsigned*)sK;
  bf16x8 qf[4];
  const unsigned* qb = q_bf + (size_t)b * 1024 + fh * 64;
#pragma unroll
  for (int s = 0; s < 4; ++s) {
    const uint4 u4 = *(const uint4*)(qb + s * 16 + fg * 4);
    BFU u; u.u[0] = u4.x; u.u[1] = u4.y; u.u[2] = u4.z; u.u[3] = u4.w;
    qf[s] = u.v;
  }
  if (t < 16) { mrun[0][t] = -1e30f; lrun[0][t] = 0.f; }
  if (has_self) {
    float sps = 0.f;
#pragma unroll
    for (int s = 0; s < 4; ++s) {
      BFU u; u.v = qf[s];
      const float* kn = kv_buf + (size_t)b * 256 + s * 32 + fg * 8;
#pragma unroll
      for (int jj = 0; jj < 4; ++jj) {
        sps = fmaf(__uint_as_float(u.u[jj] << 16), kn[2 * jj], sps);
        sps = fmaf(__uint_as_float(u.u[jj] & 0xffff0000u), kn[2 * jj + 1], sps);
      }
    }
    sps += __shfl_xor(sps, 16, 64);
    sps += __shfl_xor(sps, 32, 64);
    if (wv == 0 && lane < 16) sself[lane] = sps;
  }

  const int ntiles = (klen + 63) >> 6;
  const float* ksrc = key_cache + (size_t)b * LCACHE * DH;
  const float* vsrc = value_cache + (size_t)b * LCACHE * DH;
  float4 kst[8], vst[8];
  if (ntiles > 0) {
    const int tb = n0 * DH;
#pragma unroll
    for (int j = 0; j < 8; ++j) {
      const int off = min(tb + j * 1024 + t * 4, LCACHE * DH - 4);
      kst[j] = *(const float4*)(ksrc + off);
    }
    const int r0 = n0 + 2 * vp;
    const float* sa = vsrc + (size_t)min(r0, LCACHE - 1) * DH + vc * 16;
    const float* sb = vsrc + (size_t)min(r0 + 1, LCACHE - 1) * DH + vc * 16;
#pragma unroll
    for (int j = 0; j < 4; ++j) {
      vst[j] = *(const float4*)(sa + j * 4);
      vst[4 + j] = *(const float4*)(sb + j * 4);
    }
  }
  __syncthreads();   // mrun/sself ready

  f32x4 oacc[2];
  oacc[0] = (f32x4){0.f, 0.f, 0.f, 0.f};
  oacc[1] = (f32x4){0.f, 0.f, 0.f, 0.f};
  int par = 0;

  for (int tt = 0; tt < ntiles; ++tt) {
    if (tt > 0) __syncthreads();
#pragma unroll
    for (int j = 0; j < 8; ++j) {
      const int row = j * 8 + (t >> 5);
      const int byteo = ((t & 31) * 8) ^ ((row & 7) << 4);
      const int w0 = row * 64 + (byteo >> 2);
      Kl32[w0] = pkbf(kst[j].x, kst[j].y);
      Kl32[w0 + 1] = pkbf(kst[j].z, kst[j].w);
    }
#pragma unroll
    for (int j = 0; j < 4; ++j) {
      const float4 a = vst[j];
      const float4 b4 = vst[4 + j];
      const int d = vc * 16 + j * 4;
      VtW[(d + 0) * 44 + vp] = pkbf(a.x, b4.x);
      VtW[(d + 1) * 44 + vp] = pkbf(a.y, b4.y);
      VtW[(d + 2) * 44 + vp] = pkbf(a.z, b4.z);
      VtW[(d + 3) * 44 + vp] = pkbf(a.w, b4.w);
    }
    if (tt + 1 < ntiles) {
      const int tb = (n0 + (tt + 1) * 64) * DH;
#pragma unroll
      for (int j = 0; j < 8; ++j) {
        const int off = min(tb + j * 1024 + t * 4, LCACHE * DH - 4);
        kst[j] = *(const float4*)(ksrc + off);
      }
      const int r0 = n0 + (tt + 1) * 64 + 2 * vp;
      const float* sa = vsrc + (size_t)min(r0, LCACHE - 1) * DH + vc * 16;
      const float* sb = vsrc + (size_t)min(r0 + 1, LCACHE - 1) * DH + vc * 16;
#pragma unroll
      for (int j = 0; j < 4; ++j) {
        vst[j] = *(const float4*)(sa + j * 4);
        vst[4 + j] = *(const float4*)(sb + j * 4);
      }
    }
    __syncthreads();

    f32x4 sacc = {0.f, 0.f, 0.f, 0.f};
    const int rr = wv * 16 + fh;
#pragma unroll
    for (int s = 0; s < 4; ++s) {
      const int off = rr * 256 + ((s * 64 + fg * 16) ^ ((rr & 7) << 4));
      const bf16x8 af = *(const bf16x8*)(sK + off);
      sacc = __builtin_amdgcn_mfma_f32_16x16x32_bf16(af, qf[s], sacc, 0, 0, 0);
    }
    const int rloc = wv * 16 + fg * 4;
    const int lim = klen - tt * 64;
    float s0 = (rloc + 0 < lim) ? sacc[0] : -1e30f;
    float s1 = (rloc + 1 < lim) ? sacc[1] : -1e30f;
    float s2 = (rloc + 2 < lim) ? sacc[2] : -1e30f;
    float s3 = (rloc + 3 < lim) ? sacc[3] : -1e30f;
    float ml = fmaxf(fmaxf(s0, s1), fmaxf(s2, s3));
    ml = fmaxf(ml, __shfl_xor(ml, 16, 64));
    ml = fmaxf(ml, __shfl_xor(ml, 32, 64));
    if (fg == 0) red1[wv * 16 + fh] = ml;
    __syncthreads();

    const float4 r0v = *(const float4*)&red1[0 + fg * 4];
    const float4 r1v = *(const float4*)&red1[16 + fg * 4];
    const float4 r2v = *(const float4*)&red1[32 + fg * 4];
    const float4 r3v = *(const float4*)&red1[48 + fg * 4];
    float mt[4];
    mt[0] = fmaxf(fmaxf(r0v.x, r1v.x), fmaxf(r2v.x, r3v.x));
    mt[1] = fmaxf(fmaxf(r0v.y, r1v.y), fmaxf(r2v.y, r3v.y));
    mt[2] = fmaxf(fmaxf(r0v.z, r1v.z), fmaxf(r2v.z, r3v.z));
    mt[3] = fmaxf(fmaxf(r0v.w, r1v.w), fmaxf(r2v.w, r3v.w));
    const float mtf = fmaxf(fmaxf(red1[fh], red1[16 + fh]), fmaxf(red1[32 + fh], red1[48 + fh]));
    const float4 mp4 = *(const float4*)&mrun[par][fg * 4];
    const float mpf = mrun[par][fh];
    const float mnf = fmaxf(mtf, mpf);
    const float p0 = __expf(s0 - mnf);
    const float p1 = __expf(s1 - mnf);
    const float p2 = __expf(s2 - mnf);
    const float p3 = __expf(s3 - mnf);
    {
      const float mpj[4] = {mp4.x, mp4.y, mp4.z, mp4.w};
#pragma unroll
      for (int j = 0; j < 4; ++j) {
        const float mn = fmaxf(mt[j], mpj[j]);
        const float rf = __expf(mpj[j] - mn);
        oacc[0][j] *= rf;
        oacc[1][j] *= rf;
      }
    }
    float sl = p0 + p1 + p2 + p3;
    sl += __shfl_xor(sl, 16, 64);
    sl += __shfl_xor(sl, 32, 64);
    if (fg == 0) red2[wv * 16 + fh] = sl;
    Pbuf[fh * 36 + wv * 8 + fg * 2] = pkbf(p0, p1);
    Pbuf[fh * 36 + wv * 8 + fg * 2 + 1] = pkbf(p2, p3);
    if (t < 16) mrun[par ^ 1][t] = mnf;
    __syncthreads();

    if (t < 16) {
      const float lsum = red2[t] + red2[16 + t] + red2[32 + t] + red2[48 + t];
      lrun[par ^ 1][t] = lrun[par][t] * __expf(mrun[par][t] - mrun[par ^ 1][t]) + lsum;
    }
#pragma unroll
    for (int c2 = 0; c2 < 2; ++c2) {
      const bf16x8 pf = *(const bf16x8*)&Pbuf[fh * 36 + c2 * 16 + fg * 4];
#pragma unroll
      for (int dt = 0; dt < 2; ++dt) {
        const int d = wv * 32 + dt * 16 + fh;
        const bf16x8 vf = *(const bf16x8*)&VtW[d * 44 + c2 * 16 + fg * 4];
        oacc[dt] = __builtin_amdgcn_mfma_f32_16x16x32_bf16(pf, vf, oacc[dt], 0, 0, 0);
      }
    }
    par ^= 1;
  }
  __syncthreads();

  const int parF = par;
  if (has_self) {
    const float4 mp4 = *(const float4*)&mrun[parF][fg * 4];
    const float4 ss4 = *(const float4*)&sself[fg * 4];
    const float vn0 = kv_buf[(size_t)b * 256 + 128 + wv * 32 + fh];
    const float vn1 = kv_buf[(size_t)b * 256 + 128 + wv * 32 + 16 + fh];
    const float mpj[4] = {mp4.x, mp4.y, mp4.z, mp4.w};
    const float ssj[4] = {ss4.x, ss4.y, ss4.z, ss4.w};
#pragma unroll
    for (int j = 0; j < 4; ++j) {
      const float mn = fmaxf(mpj[j], ssj[j]);
      const float rf = __expf(mpj[j] - mn);
      const float ps = __expf(ssj[j] - mn);
      oacc[0][j] = oacc[0][j] * rf + ps * vn0;
      oacc[1][j] = oacc[1][j] * rf + ps * vn1;
    }
    if (t < 16) {
      const float mp = mrun[parF][t], ss = sself[t];
      const float mn = fmaxf(mp, ss);
      part_m[((size_t)b * NS + sp) * H + t] = mn;
      part_l[((size_t)b * NS + sp) * H + t] =
          lrun[parF][t] * __expf(mp - mn) + __expf(ss - mn);
    }
  } else {
    if (t < 16) {
      part_m[((size_t)b * NS + sp) * H + t] = mrun[parF][t];
      part_l[((size_t)b * NS + sp) * H + t] = lrun[parF][t];
    }
  }
  float* po = part_out + ((size_t)b * NS + sp) * H * DH;
#pragma unroll
  for (int dt = 0; dt < 2; ++dt) {
    const int d = wv * 32 + dt * 16 + fh;
#pragma unroll
    for (int j = 0; j < 4; ++j) po[(size_t)(fg * 4 + j) * DH + d] = oacc[dt][j];
  }
}

// ============ merge flash-decoding splits -> ctx_buf [64][2048] ============
__global__ __launch_bounds__(256) void attn_combine(
    const float* __restrict__ part_out, const float* __restrict__ part_m,
    const float* __restrict__ part_l, float* __restrict__ ctx_buf) {
  const int b = blockIdx.x;
  const int dq = blockIdx.y;
  const int t = threadIdx.x;
  const int h = t >> 4;
  const int d = dq * 32 + (t & 15) * 2;
  float M = -1e30f;
#pragma unroll
  for (int sp = 0; sp < NS; ++sp)
    M = fmaxf(M, part_m[((size_t)b * NS + sp) * H + h]);
  float L = 0.f, o0 = 0.f, o1 = 0.f;
#pragma unroll
  for (int sp = 0; sp < NS; ++sp) {
    const float m = part_m[((size_t)b * NS + sp) * H + h];
    if (m < -1e29f) continue;
    const float w = __expf(m - M);
    L += w * part_l[((size_t)b * NS + sp) * H + h];
    const float2 a = *(const float2*)(part_out + (((size_t)b * NS + sp) * H + h) * DH + d);
    o0 = fmaf(w, a.x, o0);
    o1 = fmaf(w, a.y, o1);
  }
  const float inv = 1.f / L;
  float* dst = ctx_buf + (size_t)b * HID + h * DH + d;
  dst[0] = o0 * inv;
  dst[1] = o1 * inv;
}

extern "C" void kernel_launch(void* const* d_in, const int* in_sizes, int n_in,
                              void* d_out, int out_size, void* d_ws, size_t ws_size,
                              hipStream_t stream) {
  const float* hidden      = (const float*)d_in[0];
  const float* key_cache   = (const float*)d_in[1];
  const float* value_cache = (const float*)d_in[2];
  const float* Wq  = (const float*)d_in[3];
  const float* bq  = (const float*)d_in[4];
  const float* Wkv = (const float*)d_in[5];
  const float* bkv = (const float*)d_in[6];
  const float* Wo  = (const float*)d_in[7];
  const float* bo  = (const float*)d_in[8];
  const int*   lens = (const int*)d_in[9];
  float* out = (float*)d_out;

  float* ws = (float*)d_ws;
  float*    part1    = ws;                                          // KS*64*2304
  unsigned* q_bf     = (unsigned*)(part1 + (size_t)KS * 64 * 2304); // 64*1024 u32
  float*    kv_buf   = (float*)(q_bf + (size_t)64 * 1024);          // 64*256
  float*    part_out = kv_buf + (size_t)64 * 256;                   // 64*NS*H*DH
  float*    part_m   = part_out + (size_t)64 * NS * H * DH;         // 64*NS*H
  float*    part_l   = part_m + (size_t)64 * NS * H;                // 64*NS*H
  float*    ctx_buf  = part_l + (size_t)64 * NS * H;                // 64*2048
  float*    part2    = ctx_buf + (size_t)64 * HID;                  // KS*64*2048

  proj_v3<0><<<dim3(18, KS), dim3(256), 0, stream>>>(hidden, Wq, Wkv, part1);
  qkv_combine<<<dim3(72), dim3(256), 0, stream>>>(part1, bq, bkv, q_bf, kv_buf);
  attn_fused<<<dim3(NS, NB), dim3(256), 0, stream>>>(
      q_bf, kv_buf, key_cache, value_cache, lens, part_out, part_m, part_l);
  attn_combine<<<dim3(NB, 4), dim3(256), 0, stream>>>(part_out, part_m, part_l, ctx_buf);
  proj_v3<1><<<dim3(16, KS), dim3(256), 0, stream>>>(ctx_buf, Wo, Wo, part2);
  wo_combine<<<dim3(128), dim3(256), 0, stream>>>(part2, bo, out);
}